// Round 7
// baseline (162.822 us; speedup 1.0000x reference)
//
#include <hip/hip_runtime.h>
#include <hip/hip_bf16.h>

typedef __attribute__((ext_vector_type(8))) short short8;
typedef __attribute__((ext_vector_type(4))) float floatx4;
typedef __attribute__((ext_vector_type(4))) unsigned int uint4v;

#define NROW 148
#define ROWB 16384                       // 4 g * 32 ch * 128B strips
#define BB   ((size_t)NROW*ROWB)         // 2,424,832 B per batch
#define COPYB ((size_t)8*BB)             // 19.4 MB per parity copy; 2 copies = 38.8 MB

__device__ __forceinline__ unsigned short f2b(float f){
  unsigned int u = __float_as_uint(f);
  unsigned int r = (u + 0x7fffu + ((u >> 16) & 1u)) >> 16;  // RNE
  return (unsigned short)r;
}

// ---------------- Kernel 1: standardize + strip-interleaved pad ----------------
// pad[rA][b][yy][g][c][128B]: byte w of strip = xs[(yy-10)%128][(32g + w/2 - rA)%128]
__global__ __launch_bounds__(256) void k_std(const float* __restrict__ x,
                                             unsigned char* __restrict__ pad){
  int bid = blockIdx.x;
  int b = bid >> 5, c = bid & 31;
  int t = threadIdx.x;
  const float* xc = x + ((size_t)(b*32 + c) << 14);
  float s = 0.f, ss = 0.f;
  #pragma unroll 4
  for (int k = 0; k < 64; ++k){
    float v = xc[t + (k << 8)];
    s += v; ss += v*v;
  }
  #pragma unroll
  for (int m = 32; m >= 1; m >>= 1){
    s  += __shfl_xor(s, m);
    ss += __shfl_xor(ss, m);
  }
  __shared__ float rs[4], rss[4], sc[2];
  int wv = t >> 6, l = t & 63;
  if (l == 0){ rs[wv] = s; rss[wv] = ss; }
  __syncthreads();
  if (t == 0){
    float S  = rs[0]+rs[1]+rs[2]+rs[3];
    float SS = rss[0]+rss[1]+rss[2]+rss[3];
    float mean = S * (1.f/16384.f);
    float var  = (SS - S*mean) * (1.f/16383.f);   // ddof=1
    float sd = sqrtf(fmaxf(var, 0.f));
    sc[0] = mean;
    sc[1] = (sd < 1e-9f) ? 0.f : 1.f/(sd*128.f);  // 1/(std*sqrt(16384))
  }
  __syncthreads();
  float mean = sc[0], scale = sc[1];
  // chunk writers: lane l -> (rA, g, kc); 16B chunk = elements 32g+8kc-rA+e
  int rA = l >> 5, u = l & 31, g = u >> 3, kc = u & 7;
  unsigned char* pb = pad + (size_t)rA*COPYB + (size_t)b*BB
                    + (unsigned)(g*4096 + c*128 + kc*16);
  int E2 = 16*g + 4*kc - rA;               // first source dword (may be -1 -> wraps)
  for (int it = 0; it < 37; ++it){
    int yy = wv*37 + it;                   // 4 waves x 37 rows = 148
    int sy = (yy + 118) & 127;             // (yy-10) mod 128
    unsigned int d0w = 0, d1w = 0;
    if (l < 32){
      const float4* src = (const float4*)(xc + (sy << 7));
      float4 v = src[l];                   // elements 4l..4l+3
      d0w = (unsigned)f2b((v.x - mean)*scale) | ((unsigned)f2b((v.y - mean)*scale) << 16);
      d1w = (unsigned)f2b((v.z - mean)*scale) | ((unsigned)f2b((v.w - mean)*scale) << 16);
    }
    unsigned int vv[5];
    #pragma unroll
    for (int k = 0; k < 5; ++k){
      int D = (E2 + k) & 63;               // source row dword index (64 dwords/row)
      unsigned int lo = (unsigned)__shfl((int)d0w, D >> 1);
      unsigned int hi = (unsigned)__shfl((int)d1w, D >> 1);
      vv[k] = (D & 1) ? hi : lo;
    }
    unsigned int o0, o1, o2, o3;
    if (rA){
      o0 = (vv[0]>>16)|(vv[1]<<16); o1 = (vv[1]>>16)|(vv[2]<<16);
      o2 = (vv[2]>>16)|(vv[3]<<16); o3 = (vv[3]>>16)|(vv[4]<<16);
    } else { o0 = vv[0]; o1 = vv[1]; o2 = vv[2]; o3 = vv[3]; }
    uint4v ov = {o0, o1, o2, o3};
    *(uint4v*)(pb + (size_t)yy*ROWB) = ov;
  }
}

// ---------------- Kernel 2: shifted Gram via MFMA, deep register pipeline ----------------
// grid: bid = (cg*2 + mh)*8 + b ; 512 blocks, 512 thr (8 waves = kq(4) x nh(2))
__global__ __launch_bounds__(512, 2) void k_corr(const unsigned char* __restrict__ pad,
                                                 float* __restrict__ out){
  __shared__ float sf[7168];
  int bid = blockIdx.x;
  int b = bid & 7;
  int r0 = bid >> 3;
  int mh = r0 & 1;
  int cg = r0 >> 1;
  int dx, d0;
  if (cg < 2){ dx = 0; d0 = cg << 2; }                 // d0 = 0, 4 (dy>=0 via symmetry)
  else { int q = cg - 2; dx = 1 + q/3; d0 = -10 + 7*(q - 3*(q/3)); }

  int tid = threadIdx.x;
  int lane = tid & 63, wvi = tid >> 6;
  int kq = wvi >> 1, nh = wvi & 1;     // kq: 32-row y strip; nh: j-half

  int rA = dx & 1;
  int sh2 = 2*(dx + rA);               // byte shift within strip; mult of 4
  int ch = lane & 15, kc = lane >> 4;
  int y0 = kq << 5;
  const unsigned char* base = pad + (size_t)b*BB;

  floatx4 acc[7];
  #pragma unroll
  for (int d = 0; d < 7; ++d) acc[d] = (floatx4)(0.f);

  for (int xi = 0; xi < 4; ++xi){
    const unsigned char* pA = base + (size_t)rA*COPYB + (size_t)(y0 + d0 + 10)*ROWB
                              + (unsigned)(xi*4096 + (mh*16 + ch)*128 + sh2 + kc*16);
    const unsigned char* pB = base + (size_t)(y0 + 10)*ROWB
                              + (unsigned)(xi*4096 + (nh*16 + ch)*128 + kc*16);
    // deep register pipeline: A ring 12 (5-step slack), B queue 6 (6-step slack)
    short8 ring[12];
    short8 BQ[6];
    #pragma unroll
    for (int w = 0; w < 11; ++w) __builtin_memcpy(&ring[w], pA + (size_t)w*ROWB, 16);
    #pragma unroll
    for (int k = 0; k < 6; ++k)  __builtin_memcpy(&BQ[k], pB + (size_t)k*ROWB, 16);
    __builtin_amdgcn_sched_group_barrier(0x20, 17, 0);   // 17 VMEM_READ up front
    #pragma unroll
    for (int yl = 0; yl < 32; ++yl){
      short8 bf = BQ[yl % 6];
      if (yl < 26) __builtin_memcpy(&BQ[yl % 6], pB + (size_t)(yl + 6)*ROWB, 16);
      if (yl < 27) __builtin_memcpy(&ring[(yl + 11) % 12], pA + (size_t)(yl + 11)*ROWB, 16);
      if (yl < 26)      __builtin_amdgcn_sched_group_barrier(0x20, 2, 0);
      else if (yl < 27) __builtin_amdgcn_sched_group_barrier(0x20, 1, 0);
      #pragma unroll
      for (int d = 0; d < 7; ++d)
        acc[d] = __builtin_amdgcn_mfma_f32_16x16x32_bf16(ring[(yl + d) % 12], bf, acc[d], 0, 0, 0);
      __builtin_amdgcn_sched_group_barrier(0x8, 7, 0);   // then 7 MFMA
    }
  }

  // ---- kq reduction via LDS tree (deterministic, no atomics) ----
  #define RIDX(d,q) ((unsigned)(((((nh*7 + (d)) << 2) + (q)) << 6) + lane))
  if (kq & 1){                          // kq 1 -> slot0, kq 3 -> slot1
    float* dst = sf + (kq >> 1)*3584;
    #pragma unroll
    for (int d = 0; d < 7; ++d)
      #pragma unroll
      for (int q = 0; q < 4; ++q) dst[RIDX(d,q)] = acc[d][q];
  }
  __syncthreads();
  if (!(kq & 1)){                       // kq0 += slot0, kq2 += slot1
    const float* src = sf + (kq >> 1)*3584;
    #pragma unroll
    for (int d = 0; d < 7; ++d)
      #pragma unroll
      for (int q = 0; q < 4; ++q) acc[d][q] += src[RIDX(d,q)];
  }
  __syncthreads();
  if (kq == 2){                         // kq2 partial -> slot0
    #pragma unroll
    for (int d = 0; d < 7; ++d)
      #pragma unroll
      for (int q = 0; q < 4; ++q) sf[RIDX(d,q)] = acc[d][q];
  }
  __syncthreads();
  if (kq == 0){
    int base_b = b * 528 * 441;
    #pragma unroll
    for (int d = 0; d < 7; ++d){
      int dy = d0 + d;
      #pragma unroll
      for (int q = 0; q < 4; ++q){
        float v = acc[d][q] + sf[RIDX(d,q)];
        int m = ((lane >> 4) << 2) + q;          // C row (M = i)
        int n = lane & 15;                        // C col (N = j)
        int i = (mh << 4) + m;
        int j = (nh << 4) + n;
        if (i <= j){
          int p = i*(65 - i)/2 + (j - i);
          out[base_b + p*441 + (10 + dy)*21 + (10 + dx)] = v;
          if (i == j && (dy != 0 || dx != 0))
            out[base_b + p*441 + (10 - dy)*21 + (10 - dx)] = v;   // autocorr symmetry
        } else {
          int p = j*(65 - j)/2 + (i - j);
          out[base_b + p*441 + (10 - dy)*21 + (10 - dx)] = v;     // pair (j,i) at (-dy,-dx)
        }
      }
    }
  }
  #undef RIDX
}

extern "C" void kernel_launch(void* const* d_in, const int* in_sizes, int n_in,
                              void* d_out, int out_size, void* d_ws, size_t ws_size,
                              hipStream_t stream){
  const float* x = (const float*)d_in[0];
  unsigned char* pad = (unsigned char*)d_ws;   // 2 copies * 19.4 MB = 38.8 MB
  float* out = (float*)d_out;
  k_std<<<dim3(256), dim3(256), 0, stream>>>(x, pad);
  k_corr<<<dim3(512), dim3(512), 0, stream>>>(pad, out);
}

// Round 8
// 91.845 us; speedup vs baseline: 1.7728x; 1.7728x over previous
//
#include <hip/hip_runtime.h>
#include <hip/hip_bf16.h>

typedef __attribute__((ext_vector_type(4))) unsigned int uint4v;
typedef __attribute__((ext_vector_type(8))) short short8;
typedef __attribute__((ext_vector_type(16))) float floatx16;

#define NROW 148
#define ROWB (20*512)                    // 10240 B per pad row (20 chunk-cols x 32ch x 16B)
#define BB   ((size_t)NROW*ROWB)         // per-batch bytes (1.51 MB)
#define STATS_OFF ((size_t)8*BB)         // 12,124,160
#define LDS_A_ROWS 38
#define LDS_BYTES (LDS_A_ROWS*2048 + 32*2048)   // 77824 + 65536 = 143360

__device__ __forceinline__ unsigned short f2b(float f){
  unsigned int u = __float_as_uint(f);
  return (unsigned short)((u + 0x7fffu + ((u >> 16) & 1u)) >> 16);  // RNE
}

// ---------------- Kernel 1: per-(b,c) mean/scale ----------------
__global__ __launch_bounds__(256) void k_stat(const float* __restrict__ x,
                                              float* __restrict__ stats){
  int bid = blockIdx.x;                  // = b*32 + c
  int t = threadIdx.x;
  const float* xc = x + ((size_t)bid << 14);
  float s = 0.f, ss = 0.f;
  #pragma unroll 4
  for (int k = 0; k < 64; ++k){
    float v = xc[t + (k << 8)];
    s += v; ss += v*v;
  }
  #pragma unroll
  for (int m = 32; m >= 1; m >>= 1){
    s  += __shfl_xor(s, m);
    ss += __shfl_xor(ss, m);
  }
  __shared__ float rs[4], rss[4];
  int wv = t >> 6, l = t & 63;
  if (l == 0){ rs[wv] = s; rss[wv] = ss; }
  __syncthreads();
  if (t == 0){
    float S  = rs[0]+rs[1]+rs[2]+rs[3];
    float SS = rss[0]+rss[1]+rss[2]+rss[3];
    float mean = S * (1.f/16384.f);
    float var  = (SS - S*mean) * (1.f/16383.f);   // ddof=1
    float sd = sqrtf(fmaxf(var, 0.f));
    stats[bid*2]   = mean;
    stats[bid*2+1] = (sd < 1e-9f) ? 0.f : 1.f/(sd*128.f);  // 1/(std*sqrt(16384))
  }
}

// ---------------- Kernel 2: standardize + chunk-interleaved pad ----------------
// pad chunk (b, r, col, ch), elements e=0..7:  xs_std[b][ch][(r-10)%128][(8*col+e)%128]
__global__ __launch_bounds__(512) void k_pack(const float* __restrict__ x,
                                              const float* __restrict__ stats,
                                              unsigned char* __restrict__ pad){
  __shared__ float rowbuf[32*129];       // +1 f32 pad per channel row -> conflict-free
  int bid = blockIdx.x;
  int b = bid & 7, rg = bid >> 3;        // rg 0..36, rows 4rg..4rg+3
  int t = threadIdx.x;
  int ch = t >> 4, xq = t & 15;
  float mean  = stats[(b*32 + ch)*2];
  float scale = stats[(b*32 + ch)*2 + 1];
  const float* xc = x + ((size_t)(b*32 + ch) << 14);
  for (int rr = 0; rr < 4; ++rr){
    int r = rg*4 + rr;
    int sy = (r + 118) & 127;            // (r-10) mod 128
    const float* src = xc + (sy << 7) + (xq << 3);
    float4 v0 = *(const float4*)src;
    float4 v1 = *(const float4*)(src + 4);
    float* rb = rowbuf + ch*129 + (xq << 3);
    rb[0] = (v0.x-mean)*scale; rb[1] = (v0.y-mean)*scale;
    rb[2] = (v0.z-mean)*scale; rb[3] = (v0.w-mean)*scale;
    rb[4] = (v1.x-mean)*scale; rb[5] = (v1.y-mean)*scale;
    rb[6] = (v1.z-mean)*scale; rb[7] = (v1.w-mean)*scale;
    __syncthreads();
    #pragma unroll
    for (int k = 0; k < 2; ++k){
      int q = t + (k << 9);
      if (q < 640){
        int col = q >> 5, cq = q & 31;
        const float* rbq = rowbuf + cq*129;
        unsigned int d[4];
        #pragma unroll
        for (int e = 0; e < 4; ++e){
          unsigned int lo = f2b(rbq[(8*col + 2*e)     & 127]);
          unsigned int hi = f2b(rbq[(8*col + 2*e + 1) & 127]);
          d[e] = lo | (hi << 16);
        }
        uint4v ov = {d[0], d[1], d[2], d[3]};
        *(uint4v*)(pad + ((size_t)(b*148 + r)*20 + col)*512 + cq*16) = ov;
      }
    }
    __syncthreads();
  }
}

// ---------------- Kernel 3: shifted Gram via 32x32x16 MFMA, phased LDS ----------------
// 256 blocks = (cg 0..31) x (b 0..7), 512 thr = 8 waves (kq 0..3 y-quarter, ks 0..1 k-half)
#define WW(k3, idx) (aw[k3][(idx)>>2][(idx)&3])
#define SHIFT_STORE(OFS, ODD) \
  { _Pragma("unroll") \
    for (int k3 = 0; k3 < 3; ++k3){ \
      int pid = tid + (k3 << 9); \
      if (pid < 1216){ \
        char* dst = As + (pid >> 5)*2048 + (pid & 31)*16; \
        _Pragma("unroll") \
        for (int c = 0; c < 4; ++c){ \
          unsigned int o0,o1,o2,o3; \
          if (ODD){ \
            o0 = (WW(k3,4*c+OFS+0)>>16)|(WW(k3,4*c+OFS+1)<<16); \
            o1 = (WW(k3,4*c+OFS+1)>>16)|(WW(k3,4*c+OFS+2)<<16); \
            o2 = (WW(k3,4*c+OFS+2)>>16)|(WW(k3,4*c+OFS+3)<<16); \
            o3 = (WW(k3,4*c+OFS+3)>>16)|(WW(k3,4*c+OFS+4)<<16); \
          } else { \
            o0 = WW(k3,4*c+OFS+0); o1 = WW(k3,4*c+OFS+1); \
            o2 = WW(k3,4*c+OFS+2); o3 = WW(k3,4*c+OFS+3); \
          } \
          uint4v ov = {o0,o1,o2,o3}; \
          *(uint4v*)(dst + c*512) = ov; \
        } \
      } \
    } }

__global__ __launch_bounds__(512, 2) void k_corr(const unsigned char* __restrict__ pad,
                                                 float* __restrict__ out){
  extern __shared__ char lds[];
  char* As = lds;                         // 38 rows x 2KB: chunk (ar, c, ch) pre-shifted by dx
  char* Bs = lds + LDS_A_ROWS*2048;       // 32 rows x 2KB: chunk (br, c, ch) unshifted
  float* sf = (float*)lds;                // epilogue reuse (32KB)

  int bid = blockIdx.x;
  int b = bid & 7, cg = bid >> 3;
  int dx, d0;
  if (cg < 2){ dx = 0; d0 = cg << 2; }                  // dy groups {0..6}, {4..10}
  else { int q = cg - 2; dx = 1 + q/3; d0 = -10 + 7*(q - 3*(q/3)); }
  int r2 = dx & 7, cwoff = dx >> 3;

  int tid = threadIdx.x;
  int lane = tid & 63, wvi = tid >> 6;
  int ks = wvi & 1, kq = wvi >> 1;
  unsigned offF = (unsigned)((2*ks + (lane >> 5))*512 + (lane & 31)*16);  // = lane*16 (+ks*1024)

  const unsigned char* pb = pad + (size_t)b*BB;

  floatx16 acc[7];
  #pragma unroll
  for (int d = 0; d < 7; ++d) acc[d] = (floatx16)(0.0f);

  uint4v aw[3][5];
  auto issueA = [&](int yi, int xi){
    int rab = 32*yi + 10 + d0;            // A-region pad-row base (>= 0, <= 110)
    int cwb = 4*xi + cwoff;
    #pragma unroll
    for (int k3 = 0; k3 < 3; ++k3){
      int pid = tid + (k3 << 9);
      if (pid < 1216){
        const unsigned char* g = pb + ((size_t)((rab + (pid >> 5))*20 + cwb))*512 + (pid & 31)*16;
        #pragma unroll
        for (int kk = 0; kk < 5; ++kk)
          aw[k3][kk] = *(const uint4v*)(g + kk*512);
      }
    }
  };

  issueA(0, 0);

  for (int t = 0; t < 16; ++t){
    int yi = t >> 2, xi = t & 3;
    __syncthreads();                      // previous tile's compute done; LDS free
    // B just-in-time loads (issued first so writeA hides part of the latency)
    uint4v bw[8];
    int rbb = 32*yi + 10;
    #pragma unroll
    for (int k8 = 0; k8 < 8; ++k8){
      int idb = tid + (k8 << 9);          // br = idb>>7, c = (idb>>5)&3, ch = idb&31
      bw[k8] = *(const uint4v*)(pb + ((size_t)((rbb + (idb >> 7))*20 + 4*xi + ((idb >> 5)&3)))*512 + (idb & 31)*16);
    }
    // write A (prefetched last tile) with uniform dx-shift
    switch (r2){
      case 0: SHIFT_STORE(0, 0); break;
      case 1: SHIFT_STORE(0, 1); break;
      case 2: SHIFT_STORE(1, 0); break;
      case 3: SHIFT_STORE(1, 1); break;
      case 4: SHIFT_STORE(2, 0); break;
      case 5: SHIFT_STORE(2, 1); break;
      case 6: SHIFT_STORE(3, 0); break;
      case 7: SHIFT_STORE(3, 1); break;
    }
    // write B
    #pragma unroll
    for (int k8 = 0; k8 < 8; ++k8){
      int idb = tid + (k8 << 9);
      *(uint4v*)(Bs + (idb >> 7)*2048 + ((idb >> 5)&3)*512 + (idb & 31)*16) = bw[k8];
    }
    __syncthreads();
    if (t < 15) issueA((t+1) >> 2, (t+1) & 3);   // prefetch next A under this compute
    // ---- compute: 8 ysteps, ring[8] A-frags, 7 dy MFMAs each ----
    const char* Ab = As + (kq*8)*2048 + offF;
    const char* Bb = Bs + (kq*8)*2048 + offF;
    short8 ring[8];
    #pragma unroll
    for (int w = 0; w < 7; ++w) ring[w] = *(const short8*)(Ab + w*2048);
    short8 bnxt = *(const short8*)Bb;
    #pragma unroll
    for (int yl = 0; yl < 8; ++yl){
      short8 bf = bnxt;
      if (yl < 7){
        bnxt = *(const short8*)(Bb + (yl+1)*2048);
        ring[(yl+7)&7] = *(const short8*)(Ab + (yl+7)*2048);
      }
      #pragma unroll
      for (int d = 0; d < 7; ++d)
        acc[d] = __builtin_amdgcn_mfma_f32_32x32x16_bf16(ring[(yl+d)&7], bf, acc[d], 0, 0, 0);
    }
  }

  // ---- epilogue: 8-wave reduce per dy, triangle-routed stores ----
  __syncthreads();
  int baseb = b * 232848;                 // 528*441
  #pragma unroll
  for (int d = 0; d < 7; ++d){
    #pragma unroll
    for (int r = 0; r < 16; ++r)
      sf[wvi*1024 + r*64 + lane] = acc[d][r];
    __syncthreads();
    int dy = d0 + d;
    #pragma unroll
    for (int k = 0; k < 2; ++k){
      int p = tid + (k << 9);
      float v = 0.f;
      #pragma unroll
      for (int w = 0; w < 8; ++w) v += sf[w*1024 + p];
      int reg = p >> 6, ln = p & 63;
      int i = (reg & 3) + 8*(reg >> 2) + 4*(ln >> 5);   // C row (M = channel i, shifted operand)
      int j = ln & 31;                                   // C col (N = channel j)
      if (i <= j){
        int pp = i*(65 - i)/2 + (j - i);
        out[baseb + pp*441 + (10+dy)*21 + (10+dx)] = v;
        if (i == j && (dy != 0 || dx != 0))
          out[baseb + pp*441 + (10-dy)*21 + (10-dx)] = v;   // autocorr symmetry
      } else {
        int pp = j*(65 - j)/2 + (i - j);
        out[baseb + pp*441 + (10-dy)*21 + (10-dx)] = v;     // pair (j,i) at (-dy,-dx)
      }
    }
    __syncthreads();
  }
}

extern "C" void kernel_launch(void* const* d_in, const int* in_sizes, int n_in,
                              void* d_out, int out_size, void* d_ws, size_t ws_size,
                              hipStream_t stream){
  const float* x = (const float*)d_in[0];
  unsigned char* pad = (unsigned char*)d_ws;             // 12.12 MB
  float* stats = (float*)((char*)d_ws + STATS_OFF);      // 256 x {mean, scale}
  float* out = (float*)d_out;
  hipFuncSetAttribute((const void*)k_corr, hipFuncAttributeMaxDynamicSharedMemorySize,
                      LDS_BYTES);
  k_stat<<<dim3(256), dim3(256), 0, stream>>>(x, stats);
  k_pack<<<dim3(296), dim3(512), 0, stream>>>(x, stats, pad);
  k_corr<<<dim3(256), dim3(512), LDS_BYTES, stream>>>(pad, out);
}

// Round 9
// 86.774 us; speedup vs baseline: 1.8764x; 1.0584x over previous
//
#include <hip/hip_runtime.h>
#include <hip/hip_bf16.h>

typedef __attribute__((ext_vector_type(4))) unsigned int uint4v;
typedef __attribute__((ext_vector_type(8))) short short8;
typedef __attribute__((ext_vector_type(16))) float floatx16;

#define NROW 148
#define ROWB (20*512)                    // 10240 B per pad row (20 chunk-cols x 32ch x 16B)
#define BB   ((size_t)NROW*ROWB)         // per-batch bytes (1.51 MB)
#define STATS_OFF ((size_t)8*BB)         // 12,124,160
#define LDS_A_ROWS 38
#define LDS_BYTES (LDS_A_ROWS*2048 + 32*2048)   // 77824 + 65536 = 143360

__device__ __forceinline__ unsigned short f2b(float f){
  unsigned int u = __float_as_uint(f);
  return (unsigned short)((u + 0x7fffu + ((u >> 16) & 1u)) >> 16);  // RNE
}

__device__ __forceinline__ void gload_lds16(const void* g, void* l){
  __builtin_amdgcn_global_load_lds((const __attribute__((address_space(1))) unsigned int*)g,
                                   (__attribute__((address_space(3))) unsigned int*)l, 16, 0, 0);
}

// ---------------- Kernel 1: per-(b,c) mean/scale ----------------
__global__ __launch_bounds__(256) void k_stat(const float* __restrict__ x,
                                              float* __restrict__ stats){
  int bid = blockIdx.x;                  // = b*32 + c
  int t = threadIdx.x;
  const float* xc = x + ((size_t)bid << 14);
  float s = 0.f, ss = 0.f;
  #pragma unroll 4
  for (int k = 0; k < 64; ++k){
    float v = xc[t + (k << 8)];
    s += v; ss += v*v;
  }
  #pragma unroll
  for (int m = 32; m >= 1; m >>= 1){
    s  += __shfl_xor(s, m);
    ss += __shfl_xor(ss, m);
  }
  __shared__ float rs[4], rss[4];
  int wv = t >> 6, l = t & 63;
  if (l == 0){ rs[wv] = s; rss[wv] = ss; }
  __syncthreads();
  if (t == 0){
    float S  = rs[0]+rs[1]+rs[2]+rs[3];
    float SS = rss[0]+rss[1]+rss[2]+rss[3];
    float mean = S * (1.f/16384.f);
    float var  = (SS - S*mean) * (1.f/16383.f);   // ddof=1
    float sd = sqrtf(fmaxf(var, 0.f));
    stats[bid*2]   = mean;
    stats[bid*2+1] = (sd < 1e-9f) ? 0.f : 1.f/(sd*128.f);  // 1/(std*sqrt(16384))
  }
}

// ---------------- Kernel 2: standardize + chunk-interleaved pad ----------------
// pad chunk (b, r, col, ch), elements e=0..7:  xs_std[b][ch][(r-10)%128][(8*col+e)%128]
__global__ __launch_bounds__(512) void k_pack(const float* __restrict__ x,
                                              const float* __restrict__ stats,
                                              unsigned char* __restrict__ pad){
  __shared__ float rowbuf[32*129];       // +1 f32 pad per channel row -> conflict-free
  int bid = blockIdx.x;
  int b = bid & 7, rg = bid >> 3;        // rg 0..36, rows 4rg..4rg+3
  int t = threadIdx.x;
  int ch = t >> 4, xq = t & 15;
  float mean  = stats[(b*32 + ch)*2];
  float scale = stats[(b*32 + ch)*2 + 1];
  const float* xc = x + ((size_t)(b*32 + ch) << 14);
  for (int rr = 0; rr < 4; ++rr){
    int r = rg*4 + rr;
    int sy = (r + 118) & 127;            // (r-10) mod 128
    const float* src = xc + (sy << 7) + (xq << 3);
    float4 v0 = *(const float4*)src;
    float4 v1 = *(const float4*)(src + 4);
    float* rb = rowbuf + ch*129 + (xq << 3);
    rb[0] = (v0.x-mean)*scale; rb[1] = (v0.y-mean)*scale;
    rb[2] = (v0.z-mean)*scale; rb[3] = (v0.w-mean)*scale;
    rb[4] = (v1.x-mean)*scale; rb[5] = (v1.y-mean)*scale;
    rb[6] = (v1.z-mean)*scale; rb[7] = (v1.w-mean)*scale;
    __syncthreads();
    #pragma unroll
    for (int k = 0; k < 2; ++k){
      int q = t + (k << 9);
      if (q < 640){
        int col = q >> 5, cq = q & 31;
        const float* rbq = rowbuf + cq*129;
        unsigned int d[4];
        #pragma unroll
        for (int e = 0; e < 4; ++e){
          unsigned int lo = f2b(rbq[(8*col + 2*e)     & 127]);
          unsigned int hi = f2b(rbq[(8*col + 2*e + 1) & 127]);
          d[e] = lo | (hi << 16);
        }
        uint4v ov = {d[0], d[1], d[2], d[3]};
        *(uint4v*)(pad + ((size_t)(b*148 + r)*20 + col)*512 + cq*16) = ov;
      }
    }
    __syncthreads();
  }
}

// ---------------- Kernel 3: shifted Gram via 32x32x16 MFMA, phased LDS ----------------
// 256 blocks = (cg 0..31) x (b 0..7), 512 thr = 8 waves (kq 0..3 y-quarter, ks 0..1 k-half)
#define WW(k3, idx) (aw[k3][(idx)>>2][(idx)&3])
#define SHIFT_STORE(OFS, ODD) \
  { _Pragma("unroll") \
    for (int k3 = 0; k3 < 3; ++k3){ \
      int pid = tid + (k3 << 9); \
      if (pid < 1216){ \
        char* dst = As + (pid >> 5)*2048 + (pid & 31)*16; \
        _Pragma("unroll") \
        for (int c = 0; c < 4; ++c){ \
          unsigned int o0,o1,o2,o3; \
          if (ODD){ \
            o0 = (WW(k3,4*c+OFS+0)>>16)|(WW(k3,4*c+OFS+1)<<16); \
            o1 = (WW(k3,4*c+OFS+1)>>16)|(WW(k3,4*c+OFS+2)<<16); \
            o2 = (WW(k3,4*c+OFS+2)>>16)|(WW(k3,4*c+OFS+3)<<16); \
            o3 = (WW(k3,4*c+OFS+3)>>16)|(WW(k3,4*c+OFS+4)<<16); \
          } else { \
            o0 = WW(k3,4*c+OFS+0); o1 = WW(k3,4*c+OFS+1); \
            o2 = WW(k3,4*c+OFS+2); o3 = WW(k3,4*c+OFS+3); \
          } \
          uint4v ov = {o0,o1,o2,o3}; \
          *(uint4v*)(dst + c*512) = ov; \
        } \
      } \
    } }

__global__ __launch_bounds__(512, 1) void k_corr(const unsigned char* __restrict__ pad,
                                                 float* __restrict__ out){
  extern __shared__ char lds[];
  char* As = lds;                         // 38 rows x 2KB: chunk (ar, c, ch) pre-shifted by dx
  char* Bs = lds + LDS_A_ROWS*2048;       // 32 rows x 2KB: chunk (br, c, ch) unshifted
  float* sf = (float*)lds;                // epilogue reuse (32KB)

  int bid = blockIdx.x;
  int b = bid & 7, cg = bid >> 3;
  int dx, d0;
  if (cg < 2){ dx = 0; d0 = cg << 2; }                  // dy groups {0..6}, {4..10}
  else { int q = cg - 2; dx = 1 + q/3; d0 = -10 + 7*(q - 3*(q/3)); }
  int r2 = dx & 7, cwoff = dx >> 3;

  int tid = threadIdx.x;
  int lane = tid & 63, wvi = tid >> 6;
  int ks = wvi & 1, kq = wvi >> 1;
  unsigned offF = (unsigned)((2*ks + (lane >> 5))*512 + (lane & 31)*16);  // = lane*16 (+ks*1024)

  const unsigned char* pb = pad + (size_t)b*BB;

  floatx16 acc[7];
  #pragma unroll
  for (int d = 0; d < 7; ++d) acc[d] = (floatx16)(0.0f);

  uint4v aw[3][5];
  auto issueA = [&](int yi, int xi){
    int rab = 32*yi + 10 + d0;            // A-region pad-row base (>= 0, <= 110)
    int cwb = 4*xi + cwoff;
    #pragma unroll
    for (int k3 = 0; k3 < 3; ++k3){
      int pid = tid + (k3 << 9);
      if (pid < 1216){
        const unsigned char* g = pb + ((size_t)((rab + (pid >> 5))*20 + cwb))*512 + (pid & 31)*16;
        #pragma unroll
        for (int kk = 0; kk < 5; ++kk)
          aw[k3][kk] = *(const uint4v*)(g + kk*512);
      }
    }
  };

  issueA(0, 0);

  for (int t = 0; t < 16; ++t){
    int yi = t >> 2, xi = t & 3;
    __syncthreads();                      // previous tile's compute done; LDS free
    // B: async DMA direct to LDS (dest = Bs + idb*16 is wave-uniform-base + lane*16)
    int rbb = 32*yi + 10;
    #pragma unroll
    for (int k8 = 0; k8 < 8; ++k8){
      int idb = tid + (k8 << 9);          // br = idb>>7, c = (idb>>5)&3, ch = idb&31
      const unsigned char* g = pb + ((size_t)((rbb + (idb >> 7))*20 + 4*xi + ((idb >> 5)&3)))*512 + (idb & 31)*16;
      gload_lds16(g, Bs + (unsigned)idb*16);
    }
    // write A (prefetched last tile) with uniform dx-shift; overlaps B DMA flight
    switch (r2){
      case 0: SHIFT_STORE(0, 0); break;
      case 1: SHIFT_STORE(0, 1); break;
      case 2: SHIFT_STORE(1, 0); break;
      case 3: SHIFT_STORE(1, 1); break;
      case 4: SHIFT_STORE(2, 0); break;
      case 5: SHIFT_STORE(2, 1); break;
      case 6: SHIFT_STORE(3, 0); break;
      case 7: SHIFT_STORE(3, 1); break;
    }
    __syncthreads();                      // drains vmcnt (B DMA) + lgkm (A writes)
    if (t < 15) issueA((t+1) >> 2, (t+1) & 3);   // prefetch next A under this compute
    // ---- compute: 8 ysteps, ring[8] A-frags, 7 dy MFMAs each ----
    const char* Ab = As + (kq*8)*2048 + offF;
    const char* Bb = Bs + (kq*8)*2048 + offF;
    short8 ring[8];
    #pragma unroll
    for (int w = 0; w < 7; ++w) ring[w] = *(const short8*)(Ab + w*2048);
    short8 bnxt = *(const short8*)Bb;
    __builtin_amdgcn_s_setprio(1);
    #pragma unroll
    for (int yl = 0; yl < 8; ++yl){
      short8 bf = bnxt;
      if (yl < 7){
        bnxt = *(const short8*)(Bb + (yl+1)*2048);
        ring[(yl+7)&7] = *(const short8*)(Ab + (yl+7)*2048);
      }
      #pragma unroll
      for (int d = 0; d < 7; ++d)
        acc[d] = __builtin_amdgcn_mfma_f32_32x32x16_bf16(ring[(yl+d)&7], bf, acc[d], 0, 0, 0);
    }
    __builtin_amdgcn_s_setprio(0);
  }

  // ---- epilogue: 8-wave reduce per dy, triangle-routed stores ----
  __syncthreads();
  int baseb = b * 232848;                 // 528*441
  #pragma unroll
  for (int d = 0; d < 7; ++d){
    #pragma unroll
    for (int r = 0; r < 16; ++r)
      sf[wvi*1024 + r*64 + lane] = acc[d][r];
    __syncthreads();
    int dy = d0 + d;
    #pragma unroll
    for (int k = 0; k < 2; ++k){
      int p = tid + (k << 9);
      float v = 0.f;
      #pragma unroll
      for (int w = 0; w < 8; ++w) v += sf[w*1024 + p];
      int reg = p >> 6, ln = p & 63;
      int i = (reg & 3) + 8*(reg >> 2) + 4*(ln >> 5);   // C row (M = channel i, shifted operand)
      int j = ln & 31;                                   // C col (N = channel j)
      if (i <= j){
        int pp = i*(65 - i)/2 + (j - i);
        out[baseb + pp*441 + (10+dy)*21 + (10+dx)] = v;
        if (i == j && (dy != 0 || dx != 0))
          out[baseb + pp*441 + (10-dy)*21 + (10-dx)] = v;   // autocorr symmetry
      } else {
        int pp = j*(65 - j)/2 + (i - j);
        out[baseb + pp*441 + (10-dy)*21 + (10-dx)] = v;     // pair (j,i) at (-dy,-dx)
      }
    }
    __syncthreads();
  }
}

extern "C" void kernel_launch(void* const* d_in, const int* in_sizes, int n_in,
                              void* d_out, int out_size, void* d_ws, size_t ws_size,
                              hipStream_t stream){
  const float* x = (const float*)d_in[0];
  unsigned char* pad = (unsigned char*)d_ws;             // 12.12 MB
  float* stats = (float*)((char*)d_ws + STATS_OFF);      // 256 x {mean, scale}
  float* out = (float*)d_out;
  hipFuncSetAttribute((const void*)k_corr, hipFuncAttributeMaxDynamicSharedMemorySize,
                      LDS_BYTES);
  k_stat<<<dim3(256), dim3(256), 0, stream>>>(x, stats);
  k_pack<<<dim3(296), dim3(512), 0, stream>>>(x, stats, pad);
  k_corr<<<dim3(256), dim3(512), LDS_BYTES, stream>>>(pad, out);
}

// Round 10
// 81.038 us; speedup vs baseline: 2.0092x; 1.0708x over previous
//
#include <hip/hip_runtime.h>
#include <hip/hip_bf16.h>

typedef __attribute__((ext_vector_type(4))) unsigned int uint4v;
typedef __attribute__((ext_vector_type(8))) short short8;
typedef __attribute__((ext_vector_type(16))) float floatx16;

#define NROW 148
#define ROWB (20*512)                    // 10240 B per pad row (20 chunk-cols x 32ch x 16B)
#define BB   ((size_t)NROW*ROWB)         // per-batch bytes (1.51 MB)
#define STATS_OFF ((size_t)8*BB)         // 12,124,160
#define LDS_A_ROWS 38
#define ABUF (LDS_A_ROWS*2048)           // 77824
#define LDS_BYTES (2*ABUF)               // 155648 (A double-buffered; B stays in regs)

__device__ __forceinline__ unsigned short f2b(float f){
  unsigned int u = __float_as_uint(f);
  return (unsigned short)((u + 0x7fffu + ((u >> 16) & 1u)) >> 16);  // RNE
}

// ---------------- Kernel 1: per-(b,c) mean/scale ----------------
__global__ __launch_bounds__(256) void k_stat(const float* __restrict__ x,
                                              float* __restrict__ stats){
  int bid = blockIdx.x;                  // = b*32 + c
  int t = threadIdx.x;
  const float* xc = x + ((size_t)bid << 14);
  float s = 0.f, ss = 0.f;
  #pragma unroll 4
  for (int k = 0; k < 64; ++k){
    float v = xc[t + (k << 8)];
    s += v; ss += v*v;
  }
  #pragma unroll
  for (int m = 32; m >= 1; m >>= 1){
    s  += __shfl_xor(s, m);
    ss += __shfl_xor(ss, m);
  }
  __shared__ float rs[4], rss[4];
  int wv = t >> 6, l = t & 63;
  if (l == 0){ rs[wv] = s; rss[wv] = ss; }
  __syncthreads();
  if (t == 0){
    float S  = rs[0]+rs[1]+rs[2]+rs[3];
    float SS = rss[0]+rss[1]+rss[2]+rss[3];
    float mean = S * (1.f/16384.f);
    float var  = (SS - S*mean) * (1.f/16383.f);   // ddof=1
    float sd = sqrtf(fmaxf(var, 0.f));
    stats[bid*2]   = mean;
    stats[bid*2+1] = (sd < 1e-9f) ? 0.f : 1.f/(sd*128.f);  // 1/(std*sqrt(16384))
  }
}

// ---------------- Kernel 2: standardize + chunk-interleaved pad ----------------
// pad chunk (b, r, col, ch), elements e=0..7:  xs_std[b][ch][(r-10)%128][(8*col+e)%128]
__global__ __launch_bounds__(512) void k_pack(const float* __restrict__ x,
                                              const float* __restrict__ stats,
                                              unsigned char* __restrict__ pad){
  __shared__ float rowbuf[32*129];       // +1 f32 pad per channel row -> conflict-free
  int bid = blockIdx.x;
  int b = bid & 7, rg = bid >> 3;        // rg 0..36, rows 4rg..4rg+3
  int t = threadIdx.x;
  int ch = t >> 4, xq = t & 15;
  float mean  = stats[(b*32 + ch)*2];
  float scale = stats[(b*32 + ch)*2 + 1];
  const float* xc = x + ((size_t)(b*32 + ch) << 14);
  for (int rr = 0; rr < 4; ++rr){
    int r = rg*4 + rr;
    int sy = (r + 118) & 127;            // (r-10) mod 128
    const float* src = xc + (sy << 7) + (xq << 3);
    float4 v0 = *(const float4*)src;
    float4 v1 = *(const float4*)(src + 4);
    float* rb = rowbuf + ch*129 + (xq << 3);
    rb[0] = (v0.x-mean)*scale; rb[1] = (v0.y-mean)*scale;
    rb[2] = (v0.z-mean)*scale; rb[3] = (v0.w-mean)*scale;
    rb[4] = (v1.x-mean)*scale; rb[5] = (v1.y-mean)*scale;
    rb[6] = (v1.z-mean)*scale; rb[7] = (v1.w-mean)*scale;
    __syncthreads();
    #pragma unroll
    for (int k = 0; k < 2; ++k){
      int q = t + (k << 9);
      if (q < 640){
        int col = q >> 5, cq = q & 31;
        const float* rbq = rowbuf + cq*129;
        unsigned int d[4];
        #pragma unroll
        for (int e = 0; e < 4; ++e){
          unsigned int lo = f2b(rbq[(8*col + 2*e)     & 127]);
          unsigned int hi = f2b(rbq[(8*col + 2*e + 1) & 127]);
          d[e] = lo | (hi << 16);
        }
        uint4v ov = {d[0], d[1], d[2], d[3]};
        *(uint4v*)(pad + ((size_t)(b*148 + r)*20 + col)*512 + cq*16) = ov;
      }
    }
    __syncthreads();
  }
}

// ---------------- Kernel 3: shifted Gram via 32x32x16 MFMA ----------------
// 256 blocks = (cg 0..31) x (b 0..7), 512 thr = 8 waves (kq 0..3 y-quarter, ks 0..1 col-half)
// A: dx-pre-shifted into double-buffered LDS (1 barrier/tile). B: direct global (L2, XCD-local).
#define WW(k3, idx) (aw[k3][(idx)>>2][(idx)&3])
#define SHIFT_STORE(OFS, ODD) \
  { _Pragma("unroll") \
    for (int k3 = 0; k3 < 3; ++k3){ \
      int pid = tid + (k3 << 9); \
      if (pid < 1216){ \
        char* dst = Asw + (pid >> 5)*2048 + (pid & 31)*16; \
        _Pragma("unroll") \
        for (int c = 0; c < 4; ++c){ \
          unsigned int o0,o1,o2,o3; \
          if (ODD){ \
            o0 = (WW(k3,4*c+OFS+0)>>16)|(WW(k3,4*c+OFS+1)<<16); \
            o1 = (WW(k3,4*c+OFS+1)>>16)|(WW(k3,4*c+OFS+2)<<16); \
            o2 = (WW(k3,4*c+OFS+2)>>16)|(WW(k3,4*c+OFS+3)<<16); \
            o3 = (WW(k3,4*c+OFS+3)>>16)|(WW(k3,4*c+OFS+4)<<16); \
          } else { \
            o0 = WW(k3,4*c+OFS+0); o1 = WW(k3,4*c+OFS+1); \
            o2 = WW(k3,4*c+OFS+2); o3 = WW(k3,4*c+OFS+3); \
          } \
          uint4v ov = {o0,o1,o2,o3}; \
          *(uint4v*)(dst + c*512) = ov; \
        } \
      } \
    } }
#define DO_SHIFT_STORE() \
  switch (r2){ \
    case 0: SHIFT_STORE(0, 0); break; \
    case 1: SHIFT_STORE(0, 1); break; \
    case 2: SHIFT_STORE(1, 0); break; \
    case 3: SHIFT_STORE(1, 1); break; \
    case 4: SHIFT_STORE(2, 0); break; \
    case 5: SHIFT_STORE(2, 1); break; \
    case 6: SHIFT_STORE(3, 0); break; \
    case 7: SHIFT_STORE(3, 1); break; \
  }

__global__ __launch_bounds__(512, 1) void k_corr(const unsigned char* __restrict__ pad,
                                                 float* __restrict__ out){
  extern __shared__ char lds[];
  char* As = lds;                         // 2 x 38 rows x 2KB, dx-pre-shifted
  float* sf = (float*)lds;                // epilogue reuse (32KB)

  int bid = blockIdx.x;
  int b = bid & 7, cg = bid >> 3;
  int dx, d0;
  if (cg < 2){ dx = 0; d0 = cg << 2; }                  // dy groups {0..6}, {4..10}
  else { int q = cg - 2; dx = 1 + q/3; d0 = -10 + 7*(q - 3*(q/3)); }
  int r2 = dx & 7, cwoff = dx >> 3;

  int tid = threadIdx.x;
  int lane = tid & 63, wvi = tid >> 6;
  int ks = wvi & 1, kq = wvi >> 1;
  unsigned offF = (unsigned)((2*ks + (lane >> 5))*512 + (lane & 31)*16);

  const unsigned char* pb = pad + (size_t)b*BB;

  floatx16 acc[7];
  #pragma unroll
  for (int d = 0; d < 7; ++d) acc[d] = (floatx16)(0.0f);

  uint4v aw[3][5];
  auto issueA = [&](int tt){
    int rab = 32*(tt >> 2) + 10 + d0;     // A-region pad-row base (0..110)
    int cwb = 4*(tt & 3) + cwoff;
    #pragma unroll
    for (int k3 = 0; k3 < 3; ++k3){
      int pid = tid + (k3 << 9);
      if (pid < 1216){
        const unsigned char* g = pb + ((size_t)((rab + (pid >> 5))*20 + cwb))*512 + (pid & 31)*16;
        #pragma unroll
        for (int kk = 0; kk < 5; ++kk)
          aw[k3][kk] = *(const uint4v*)(g + kk*512);
      }
    }
  };

  // prologue: stage tile 0 into buf0, prefetch tile 1 regs
  issueA(0);
  { char* Asw = As; DO_SHIFT_STORE(); }
  issueA(1);
  __syncthreads();

  for (int t = 0; t < 16; ++t){
    // stage tile t+1 into the other buffer (from regs prefetched last iter)
    if (t < 15){ char* Asw = As + ((t+1)&1)*ABUF; DO_SHIFT_STORE(); }
    if (t < 14) issueA(t+2);
    // ---- compute tile t: A from LDS buf (t&1), B direct from global ----
    const char* Ab = As + (t&1)*ABUF + (kq*8)*2048 + offF;
    const unsigned char* pBw = pb + ((size_t)((32*(t>>2) + 10 + kq*8)*20 + 4*(t&3) + 2*ks))*512
                               + (unsigned)((lane >> 5)*512 + (lane & 31)*16);
    short8 ring[8];
    #pragma unroll
    for (int w = 0; w < 7; ++w) ring[w] = *(const short8*)(Ab + w*2048);
    short8 BQ[3];
    #pragma unroll
    for (int k = 0; k < 3; ++k) BQ[k] = *(const short8*)(pBw + (size_t)k*ROWB);
    __builtin_amdgcn_s_setprio(1);
    #pragma unroll
    for (int yl = 0; yl < 8; ++yl){
      short8 bf = BQ[yl % 3];
      if (yl < 5) BQ[yl % 3] = *(const short8*)(pBw + (size_t)(yl + 3)*ROWB);
      if (yl < 7) ring[(yl+7)&7] = *(const short8*)(Ab + (yl+7)*2048);
      #pragma unroll
      for (int d = 0; d < 7; ++d)
        acc[d] = __builtin_amdgcn_mfma_f32_32x32x16_bf16(ring[(yl+d)&7], bf, acc[d], 0, 0, 0);
    }
    __builtin_amdgcn_s_setprio(0);
    __syncthreads();                      // stage(t+1) visible; buf(t&1) free for t+2
  }

  // ---- epilogue: 8-wave reduce per dy, triangle-routed stores ----
  int baseb = b * 232848;                 // 528*441
  #pragma unroll
  for (int d = 0; d < 7; ++d){
    #pragma unroll
    for (int r = 0; r < 16; ++r)
      sf[wvi*1024 + r*64 + lane] = acc[d][r];
    __syncthreads();
    int dy = d0 + d;
    #pragma unroll
    for (int k = 0; k < 2; ++k){
      int p = tid + (k << 9);
      float v = 0.f;
      #pragma unroll
      for (int w = 0; w < 8; ++w) v += sf[w*1024 + p];
      int reg = p >> 6, ln = p & 63;
      int i = (reg & 3) + 8*(reg >> 2) + 4*(ln >> 5);   // C row (M = channel i, shifted operand)
      int j = ln & 31;                                   // C col (N = channel j)
      if (i <= j){
        int pp = i*(65 - i)/2 + (j - i);
        out[baseb + pp*441 + (10+dy)*21 + (10+dx)] = v;
        if (i == j && (dy != 0 || dx != 0))
          out[baseb + pp*441 + (10-dy)*21 + (10-dx)] = v;   // autocorr symmetry
      } else {
        int pp = j*(65 - j)/2 + (i - j);
        out[baseb + pp*441 + (10-dy)*21 + (10-dx)] = v;     // pair (j,i) at (-dy,-dx)
      }
    }
    __syncthreads();
  }
}

extern "C" void kernel_launch(void* const* d_in, const int* in_sizes, int n_in,
                              void* d_out, int out_size, void* d_ws, size_t ws_size,
                              hipStream_t stream){
  const float* x = (const float*)d_in[0];
  unsigned char* pad = (unsigned char*)d_ws;             // 12.12 MB
  float* stats = (float*)((char*)d_ws + STATS_OFF);      // 256 x {mean, scale}
  float* out = (float*)d_out;
  hipFuncSetAttribute((const void*)k_corr, hipFuncAttributeMaxDynamicSharedMemorySize,
                      LDS_BYTES);
  k_stat<<<dim3(256), dim3(256), 0, stream>>>(x, stats);
  k_pack<<<dim3(296), dim3(512), 0, stream>>>(x, stats, pad);
  k_corr<<<dim3(256), dim3(512), LDS_BYTES, stream>>>(pad, out);
}